// Round 1
// baseline (202.525 us; speedup 1.0000x reference)
//
#include <hip/hip_runtime.h>

#define LSEQ 1024
#define INDIM 256
#define DM 32
#define PD 64
#define JT 256

__device__ __forceinline__ void fma4(float4& a, float s, const float4& t) {
  a.x = fmaf(s, t.x, a.x); a.y = fmaf(s, t.y, a.y);
  a.z = fmaf(s, t.z, a.z); a.w = fmaf(s, t.w, a.w);
}

// s[i][c] = seq[i,:] @ W1[:,c] + b1[c]; also sT[c][i] = s[i][c]
__global__ __launch_bounds__(256) void k_proj(const float* __restrict__ seq,
    const float* __restrict__ W1, const float* __restrict__ b1,
    float* __restrict__ s, float* __restrict__ sT) {
  __shared__ float row[8][INDIM];
  int i0 = blockIdx.x * 8;
  #pragma unroll
  for (int k = 0; k < 8; ++k) {
    int idx = k * 256 + threadIdx.x;
    row[idx >> 8][idx & 255] = seq[(size_t)i0 * INDIM + idx];
  }
  __syncthreads();
  int c = threadIdx.x & 31;
  int il = threadIdx.x >> 5;
  float acc = b1[c];
  #pragma unroll 8
  for (int d = 0; d < INDIM; ++d) acc = fmaf(row[il][d], W1[d * DM + c], acc);
  int i = i0 + il;
  s[i * DM + c] = acc;
  sT[c * LSEQ + i] = acc;
}

// t[i][c][p] = sum_d s[i][d] * W2[(c*DM+d)*PD + p]
__global__ __launch_bounds__(256) void k_t(const float* __restrict__ s,
    const float* __restrict__ W2, float* __restrict__ t_out) {
  int i = blockIdx.x;
  __shared__ float si[DM];
  if (threadIdx.x < DM) si[threadIdx.x] = s[i * DM + threadIdx.x];
  __syncthreads();
  int p = threadIdx.x & 63;
  int c0 = threadIdx.x >> 6;
  #pragma unroll
  for (int k = 0; k < 8; ++k) {
    int c = c0 * 8 + k;
    float acc = 0.f;
    #pragma unroll
    for (int d = 0; d < DM; ++d)
      acc = fmaf(si[d], W2[(c * DM + d) * PD + p], acc);
    t_out[(size_t)i * (DM * PD) + c * PD + p] = acc;
  }
}

// out[i][j][p] = sum_c t[i][c][p]*s[j][c] + b2[p] + pair[i][j][p]
// one block: fixed i, JT=256 j's, all 64 p. thread tile: 8j x 8p.
template<bool TPRE>
__global__ __launch_bounds__(256) void k_main(const float* __restrict__ s,
    const float* __restrict__ sT, const float* __restrict__ tg,
    const float* __restrict__ W2, const float* __restrict__ b2,
    const float* __restrict__ pair, float* __restrict__ out) {
  __shared__ float t_lds[DM][PD];    // 8 KB
  __shared__ float s_lds[DM][JT];    // 32 KB  (total 40 KB -> 4 blocks/CU)
  int bid = blockIdx.x;
  int i = bid >> 2;
  int jt = (bid & 3) * JT;
  int tid = threadIdx.x;

  if constexpr (TPRE) {
    // stage precomputed t[i] : 2048 floats = 512 float4
    const float4* tsrc = (const float4*)(tg + (size_t)i * (DM * PD));
    float4* tdst = (float4*)&t_lds[0][0];
    tdst[tid] = tsrc[tid];
    tdst[tid + 256] = tsrc[tid + 256];
  } else {
    // compute t[i] in-block from W2 (L2-resident)
    float* si = &s_lds[0][0];   // overlay; overwritten by s-stage later
    if (tid < DM) si[tid] = s[i * DM + tid];
    __syncthreads();
    int p = tid & 63;
    int c0 = tid >> 6;
    #pragma unroll
    for (int k = 0; k < 8; ++k) {
      int c = c0 * 8 + k;
      float acc = 0.f;
      #pragma unroll
      for (int d = 0; d < DM; ++d)
        acc = fmaf(si[d], W2[(c * DM + d) * PD + p], acc);
      t_lds[c][p] = acc;
    }
    __syncthreads();  // si reads done before s-stage clobbers it
  }

  // stage sT tile: s_lds[c][j] = sT[c][jt+j], 2048 float4, coalesced
  {
    float4* sdst = (float4*)&s_lds[0][0];
    #pragma unroll
    for (int k = 0; k < 8; ++k) {
      int idx = k * 256 + tid;
      int c = idx >> 6, j4 = idx & 63;
      sdst[idx] = ((const float4*)(sT + (size_t)c * LSEQ + jt))[j4];
    }
  }
  __syncthreads();

  int pl = tid & 7;     // p-lane: covers p = pl*4..pl*4+3 and 32+pl*4..
  int jg = tid >> 3;    // 0..31: j = jt + jg*8 + (0..7)
  float4 acc0[8], acc1[8];
  #pragma unroll
  for (int jj = 0; jj < 8; ++jj) {
    acc0[jj] = make_float4(0.f, 0.f, 0.f, 0.f);
    acc1[jj] = make_float4(0.f, 0.f, 0.f, 0.f);
  }
  const float4* t4 = (const float4*)&t_lds[0][0];  // [c*16 + pidx]
  const float4* s4 = (const float4*)&s_lds[0][0];  // [c*64 + j4]

  #pragma unroll 8
  for (int c = 0; c < DM; ++c) {
    float4 t0 = t4[c * 16 + pl];
    float4 t1 = t4[c * 16 + 8 + pl];
    float4 sA = s4[c * 64 + jg * 2];
    float4 sB = s4[c * 64 + jg * 2 + 1];
    fma4(acc0[0], sA.x, t0); fma4(acc1[0], sA.x, t1);
    fma4(acc0[1], sA.y, t0); fma4(acc1[1], sA.y, t1);
    fma4(acc0[2], sA.z, t0); fma4(acc1[2], sA.z, t1);
    fma4(acc0[3], sA.w, t0); fma4(acc1[3], sA.w, t1);
    fma4(acc0[4], sB.x, t0); fma4(acc1[4], sB.x, t1);
    fma4(acc0[5], sB.y, t0); fma4(acc1[5], sB.y, t1);
    fma4(acc0[6], sB.z, t0); fma4(acc1[6], sB.z, t1);
    fma4(acc0[7], sB.w, t0); fma4(acc1[7], sB.w, t1);
  }

  const float4* b24 = (const float4*)b2;
  float4 b0 = b24[pl], b1v = b24[8 + pl];
  size_t rowbase = (size_t)i * LSEQ * PD;
  #pragma unroll
  for (int jj = 0; jj < 8; ++jj) {
    int j = jt + jg * 8 + jj;
    const float4* pp = (const float4*)(pair + rowbase + (size_t)j * PD);
    float4* po = (float4*)(out + rowbase + (size_t)j * PD);
    float4 p0 = pp[pl], p1 = pp[8 + pl];
    float4 o0, o1;
    o0.x = acc0[jj].x + b0.x + p0.x;  o0.y = acc0[jj].y + b0.y + p0.y;
    o0.z = acc0[jj].z + b0.z + p0.z;  o0.w = acc0[jj].w + b0.w + p0.w;
    o1.x = acc1[jj].x + b1v.x + p1.x; o1.y = acc1[jj].y + b1v.y + p1.y;
    o1.z = acc1[jj].z + b1v.z + p1.z; o1.w = acc1[jj].w + b1v.w + p1.w;
    po[pl] = o0;
    po[8 + pl] = o1;
  }
}

extern "C" void kernel_launch(void* const* d_in, const int* in_sizes, int n_in,
                              void* d_out, int out_size, void* d_ws, size_t ws_size,
                              hipStream_t stream) {
  const float* seq  = (const float*)d_in[0];
  const float* pair = (const float*)d_in[1];
  const float* W1   = (const float*)d_in[2];
  const float* b1   = (const float*)d_in[3];
  const float* W2   = (const float*)d_in[4];
  const float* b2   = (const float*)d_in[5];
  float* out = (float*)d_out;
  float* ws  = (float*)d_ws;

  float* s  = ws;                      // 1024*32 floats
  float* sT = ws + LSEQ * DM;          // 32*1024 floats
  float* t  = ws + 2 * LSEQ * DM;      // 1024*32*64 floats (8 MB)
  size_t need_pre = (size_t)(2 * LSEQ * DM + LSEQ * DM * PD) * sizeof(float);

  k_proj<<<LSEQ / 8, 256, 0, stream>>>(seq, W1, b1, s, sT);
  if (ws_size >= need_pre) {
    k_t<<<LSEQ, 256, 0, stream>>>(s, W2, t);
    k_main<true><<<LSEQ * (LSEQ / JT), 256, 0, stream>>>(s, sT, t, W2, b2, pair, out);
  } else {
    k_main<false><<<LSEQ * (LSEQ / JT), 256, 0, stream>>>(s, sT, nullptr, W2, b2, pair, out);
  }
}

// Round 3
// 154.795 us; speedup vs baseline: 1.3083x; 1.3083x over previous
//
#include <hip/hip_runtime.h>

#define LSEQ 1024
#define INDIM 256
#define DM 32
#define PD 64
#define JT 128
#define NJT (LSEQ / JT)   // 8

typedef float f32x4 __attribute__((ext_vector_type(4)));

__device__ __forceinline__ void fma4(f32x4& a, float s, const f32x4& t) {
  a.x = fmaf(s, t.x, a.x); a.y = fmaf(s, t.y, a.y);
  a.z = fmaf(s, t.z, a.z); a.w = fmaf(s, t.w, a.w);
}

// Fused prep: one block per i.
//   s[i][c] = seq[i,:]@W1[:,c] + b1[c]   (kept in LDS, also written to sT[c][i])
//   t[i][c][p] = sum_d s[i][d] * W2[(c*DM+d)*PD+p]
template<bool WRT>
__global__ __launch_bounds__(256) void k_prep(const float* __restrict__ seq,
    const float* __restrict__ W1, const float* __restrict__ b1,
    const float* __restrict__ W2, float* __restrict__ sT,
    float* __restrict__ t_out) {
  int i = blockIdx.x;
  int tid = threadIdx.x;
  __shared__ float srow[INDIM];
  __shared__ float part[8][DM];
  __shared__ float si[DM];
  if (tid < 64) ((f32x4*)srow)[tid] = ((const f32x4*)(seq + (size_t)i * INDIM))[tid];
  __syncthreads();
  {
    int c = tid & 31, dseg = tid >> 5;
    float a = 0.f;
    #pragma unroll
    for (int d = 0; d < 32; ++d)
      a = fmaf(srow[dseg * 32 + d], W1[(dseg * 32 + d) * DM + c], a);
    part[dseg][c] = a;
  }
  __syncthreads();
  if (tid < DM) {
    float a = b1[tid];
    #pragma unroll
    for (int k = 0; k < 8; ++k) a += part[k][tid];
    si[tid] = a;
    sT[tid * LSEQ + i] = a;
  }
  __syncthreads();
  if constexpr (WRT) {
    int p = tid & 63, c0 = tid >> 6;
    #pragma unroll
    for (int k = 0; k < 8; ++k) {
      int c = c0 * 8 + k;
      float acc = 0.f;
      #pragma unroll
      for (int d = 0; d < DM; ++d)
        acc = fmaf(si[d], W2[(c * DM + d) * PD + p], acc);
      t_out[(size_t)i * (DM * PD) + c * PD + p] = acc;
    }
  }
}

// out[i][j][p] = sum_c t[i][c][p]*s[j][c] + b2[p] + pair[i][j][p]
// block: fixed i, JT=128 j's, all 64 p; thread tile 4j x 8p.
template<bool TPRE>
__global__ __launch_bounds__(256, 5) void k_main(const float* __restrict__ sT,
    const float* __restrict__ tg, const float* __restrict__ W2,
    const float* __restrict__ b2, const float* __restrict__ pair,
    float* __restrict__ out) {
  __shared__ float t_lds[DM][PD];    // 8 KB
  __shared__ float s_lds[DM][JT];    // 16 KB -> 24 KB total
  int bid = blockIdx.x;
  int i = bid >> 3;
  int jt = (bid & (NJT - 1)) * JT;
  int tid = threadIdx.x;

  if constexpr (TPRE) {
    const f32x4* tsrc = (const f32x4*)(tg + (size_t)i * (DM * PD));
    f32x4* tdst = (f32x4*)&t_lds[0][0];
    tdst[tid] = tsrc[tid];
    tdst[tid + 256] = tsrc[tid + 256];
  } else {
    __shared__ float si[DM];
    if (tid < DM) si[tid] = sT[tid * LSEQ + i];
    __syncthreads();
    int p = tid & 63, c0 = tid >> 6;
    #pragma unroll
    for (int k = 0; k < 8; ++k) {
      int c = c0 * 8 + k;
      float acc = 0.f;
      #pragma unroll
      for (int d = 0; d < DM; ++d)
        acc = fmaf(si[d], W2[(c * DM + d) * PD + p], acc);
      t_lds[c][p] = acc;
    }
  }

  // stage s tile: s_lds[c][j] = sT[c][jt+j]; 1024 float4, L2-resident source
  #pragma unroll
  for (int k = 0; k < 4; ++k) {
    int idx = k * 256 + tid;
    int c = idx >> 5, j4 = idx & 31;
    ((f32x4*)&s_lds[0][0])[idx] =
        ((const f32x4*)(sT + (size_t)c * LSEQ + jt))[j4];
  }
  __syncthreads();

  int pl = tid & 7;     // p = pl*4..+3 and 32+pl*4..+3
  int jg = tid >> 3;    // 0..31: j = jt + jg*4 + (0..3)

  // prefetch pair tile into registers: in flight during the c-loop
  size_t rowbase = (size_t)i * LSEQ * PD + (size_t)(jt + jg * 4) * PD;
  const f32x4* pp = (const f32x4*)(pair + rowbase);
  f32x4 pf0[4], pf1[4];
  #pragma unroll
  for (int jj = 0; jj < 4; ++jj) {
    pf0[jj] = __builtin_nontemporal_load(&pp[jj * 16 + pl]);
    pf1[jj] = __builtin_nontemporal_load(&pp[jj * 16 + 8 + pl]);
  }

  f32x4 acc0[4], acc1[4];
  #pragma unroll
  for (int jj = 0; jj < 4; ++jj) {
    acc0[jj] = (f32x4)(0.f);
    acc1[jj] = (f32x4)(0.f);
  }
  const f32x4* t4 = (const f32x4*)&t_lds[0][0];  // [c*16 + pidx]
  const f32x4* s4 = (const f32x4*)&s_lds[0][0];  // [c*32 + jg]

  #pragma unroll 8
  for (int c = 0; c < DM; ++c) {
    f32x4 t0 = t4[c * 16 + pl];
    f32x4 t1 = t4[c * 16 + 8 + pl];
    f32x4 sA = s4[c * 32 + jg];
    fma4(acc0[0], sA.x, t0); fma4(acc1[0], sA.x, t1);
    fma4(acc0[1], sA.y, t0); fma4(acc1[1], sA.y, t1);
    fma4(acc0[2], sA.z, t0); fma4(acc1[2], sA.z, t1);
    fma4(acc0[3], sA.w, t0); fma4(acc1[3], sA.w, t1);
  }

  const f32x4* b24 = (const f32x4*)b2;
  f32x4 b0 = b24[pl], b1v = b24[8 + pl];
  f32x4* po = (f32x4*)(out + rowbase);
  #pragma unroll
  for (int jj = 0; jj < 4; ++jj) {
    f32x4 o0 = acc0[jj] + b0 + pf0[jj];
    f32x4 o1 = acc1[jj] + b1v + pf1[jj];
    __builtin_nontemporal_store(o0, &po[jj * 16 + pl]);
    __builtin_nontemporal_store(o1, &po[jj * 16 + 8 + pl]);
  }
}

extern "C" void kernel_launch(void* const* d_in, const int* in_sizes, int n_in,
                              void* d_out, int out_size, void* d_ws, size_t ws_size,
                              hipStream_t stream) {
  const float* seq  = (const float*)d_in[0];
  const float* pair = (const float*)d_in[1];
  const float* W1   = (const float*)d_in[2];
  const float* b1   = (const float*)d_in[3];
  const float* W2   = (const float*)d_in[4];
  const float* b2   = (const float*)d_in[5];
  float* out = (float*)d_out;
  float* ws  = (float*)d_ws;

  float* sT = ws;                       // 32*1024 floats (128 KB)
  float* t  = ws + DM * LSEQ;           // 1024*32*64 floats (8 MB)
  size_t need = (size_t)(DM * LSEQ + (size_t)LSEQ * DM * PD) * sizeof(float);

  if (ws_size >= need) {
    k_prep<true><<<LSEQ, 256, 0, stream>>>(seq, W1, b1, W2, sT, t);
    k_main<true><<<LSEQ * NJT, 256, 0, stream>>>(sT, t, W2, b2, pair, out);
  } else {
    k_prep<false><<<LSEQ, 256, 0, stream>>>(seq, W1, b1, W2, sT, nullptr);
    k_main<false><<<LSEQ * NJT, 256, 0, stream>>>(sT, nullptr, W2, b2, pair, out);
  }
}

// Round 4
// 130.080 us; speedup vs baseline: 1.5569x; 1.1900x over previous
//
#include <hip/hip_runtime.h>

#define LSEQ 1024
#define INDIM 256
#define DM 32
#define PD 64
#define JT 128
#define NJT (LSEQ / JT)   // 8

typedef float f32x4 __attribute__((ext_vector_type(4)));

__device__ __forceinline__ void fma4(f32x4& a, float s, const f32x4& t) {
  a.x = fmaf(s, t.x, a.x); a.y = fmaf(s, t.y, a.y);
  a.z = fmaf(s, t.z, a.z); a.w = fmaf(s, t.w, a.w);
}

// Fused prep, 4 rows per block:
//   s[i][c] = seq[i,:]@W1[:,c] + b1[c]  -> sT[c][i]
//   t[i][c][p] = sum_d s[i][d] * W2[(c*DM+d)*PD+p]   (W2 read once per block)
template<bool WRT>
__global__ __launch_bounds__(256) void k_prep(const float* __restrict__ seq,
    const float* __restrict__ W1, const float* __restrict__ b1,
    const float* __restrict__ W2, float* __restrict__ sT,
    float* __restrict__ t_out) {
  int i0 = blockIdx.x * 4;
  int tid = threadIdx.x;
  __shared__ float srow[4][INDIM];
  __shared__ float part[4][2][DM];
  __shared__ float si[4][DM];
  ((f32x4*)&srow[0][0])[tid] =
      ((const f32x4*)(seq + (size_t)i0 * INDIM))[tid];
  __syncthreads();
  {
    int c = tid & 31, dseg = (tid >> 5) & 1, il = tid >> 6;
    float a = 0.f;
    #pragma unroll 16
    for (int d = 0; d < 128; ++d)
      a = fmaf(srow[il][dseg * 128 + d], W1[(dseg * 128 + d) * DM + c], a);
    part[il][dseg][c] = a;
  }
  __syncthreads();
  if (tid < 128) {
    int il = tid >> 5, c = tid & 31;
    float a = b1[c] + part[il][0][c] + part[il][1][c];
    si[il][c] = a;
    sT[c * LSEQ + i0 + il] = a;
  }
  __syncthreads();
  if constexpr (WRT) {
    int p = tid & 63, c0 = tid >> 6;
    #pragma unroll
    for (int k = 0; k < 8; ++k) {
      int c = c0 * 8 + k;
      float a0 = 0.f, a1 = 0.f, a2 = 0.f, a3 = 0.f;
      #pragma unroll
      for (int d = 0; d < DM; ++d) {
        float w = W2[(c * DM + d) * PD + p];
        a0 = fmaf(si[0][d], w, a0);
        a1 = fmaf(si[1][d], w, a1);
        a2 = fmaf(si[2][d], w, a2);
        a3 = fmaf(si[3][d], w, a3);
      }
      t_out[((size_t)(i0 + 0) * DM + c) * PD + p] = a0;
      t_out[((size_t)(i0 + 1) * DM + c) * PD + p] = a1;
      t_out[((size_t)(i0 + 2) * DM + c) * PD + p] = a2;
      t_out[((size_t)(i0 + 3) * DM + c) * PD + p] = a3;
    }
  }
}

// out[i][j][p] = sum_c t[i][c][p]*s[j][c] + b2[p] + pair[i][j][p]
// pair is loaded DIRECTLY into the accumulators at kernel start (no extra
// prefetch registers, no epilogue load stall). Thread tile 4j x 8p.
template<bool TPRE>
__global__ __launch_bounds__(256) void k_main(const float* __restrict__ sT,
    const float* __restrict__ tg, const float* __restrict__ W2,
    const float* __restrict__ b2, const float* __restrict__ pair,
    float* __restrict__ out) {
  __shared__ float t_lds[DM][PD];    // 8 KB
  __shared__ float s_lds[DM][JT];    // 16 KB
  int tid = threadIdx.x;
  // XCD-chunked swizzle: 8 same-i blocks land on one XCD (t[i] L2 reuse),
  // each XCD streams a disjoint 128-row band of pair. 8192 % 8 == 0.
  int bid = ((blockIdx.x & 7) << 10) + (blockIdx.x >> 3);
  int i = bid >> 3;
  int jt = (bid & (NJT - 1)) * JT;
  int pl = tid & 7;     // p = pl*4..+3 and 32+pl*4..+3
  int jg = tid >> 3;    // j = jt + jg*4 + (0..3)

  // 1) issue pair loads straight into accumulators, first thing
  size_t rowbase = (size_t)i * (LSEQ * PD) + (size_t)(jt + jg * 4) * PD;
  const f32x4* pp = (const f32x4*)(pair + rowbase);
  f32x4 acc0[4], acc1[4];
  #pragma unroll
  for (int jj = 0; jj < 4; ++jj) {
    acc0[jj] = __builtin_nontemporal_load(&pp[jj * 16 + pl]);
    acc1[jj] = __builtin_nontemporal_load(&pp[jj * 16 + 8 + pl]);
  }
  const f32x4* b24 = (const f32x4*)b2;
  f32x4 b0 = b24[pl], b1v = b24[8 + pl];
  __builtin_amdgcn_sched_barrier(0);   // keep these loads issued up front

  // 2) stage t[i] and s tile into LDS (latency overlaps pair loads)
  if constexpr (TPRE) {
    const f32x4* tsrc = (const f32x4*)(tg + (size_t)i * (DM * PD));
    f32x4* tdst = (f32x4*)&t_lds[0][0];
    tdst[tid] = tsrc[tid];
    tdst[tid + 256] = tsrc[tid + 256];
  } else {
    __shared__ float sish[DM];
    if (tid < DM) sish[tid] = sT[tid * LSEQ + i];
    __syncthreads();
    int p = tid & 63, c0 = tid >> 6;
    #pragma unroll
    for (int k = 0; k < 8; ++k) {
      int c = c0 * 8 + k;
      float acc = 0.f;
      #pragma unroll
      for (int d = 0; d < DM; ++d)
        acc = fmaf(sish[d], W2[(c * DM + d) * PD + p], acc);
      t_lds[c][p] = acc;
    }
  }
  #pragma unroll
  for (int k = 0; k < 4; ++k) {
    int idx = k * 256 + tid;
    int c = idx >> 5, j4 = idx & 31;
    ((f32x4*)&s_lds[0][0])[idx] =
        ((const f32x4*)(sT + (size_t)c * LSEQ + jt))[j4];
  }
  __syncthreads();

  // 3) fold bias into accumulators (pair loads complete by the barrier)
  #pragma unroll
  for (int jj = 0; jj < 4; ++jj) { acc0[jj] += b0; acc1[jj] += b1v; }

  // 4) contraction over c
  const f32x4* t4 = (const f32x4*)&t_lds[0][0];  // [c*16 + pidx]
  const f32x4* s4 = (const f32x4*)&s_lds[0][0];  // [c*32 + jg]
  #pragma unroll 8
  for (int c = 0; c < DM; ++c) {
    f32x4 t0 = t4[c * 16 + pl];
    f32x4 t1 = t4[c * 16 + 8 + pl];
    f32x4 sA = s4[c * 32 + jg];
    fma4(acc0[0], sA.x, t0); fma4(acc1[0], sA.x, t1);
    fma4(acc0[1], sA.y, t0); fma4(acc1[1], sA.y, t1);
    fma4(acc0[2], sA.z, t0); fma4(acc1[2], sA.z, t1);
    fma4(acc0[3], sA.w, t0); fma4(acc1[3], sA.w, t1);
  }

  // 5) pure stores, no pending loads
  f32x4* po = (f32x4*)(out + rowbase);
  #pragma unroll
  for (int jj = 0; jj < 4; ++jj) {
    __builtin_nontemporal_store(acc0[jj], &po[jj * 16 + pl]);
    __builtin_nontemporal_store(acc1[jj], &po[jj * 16 + 8 + pl]);
  }
}

extern "C" void kernel_launch(void* const* d_in, const int* in_sizes, int n_in,
                              void* d_out, int out_size, void* d_ws, size_t ws_size,
                              hipStream_t stream) {
  const float* seq  = (const float*)d_in[0];
  const float* pair = (const float*)d_in[1];
  const float* W1   = (const float*)d_in[2];
  const float* b1   = (const float*)d_in[3];
  const float* W2   = (const float*)d_in[4];
  const float* b2   = (const float*)d_in[5];
  float* out = (float*)d_out;
  float* ws  = (float*)d_ws;

  float* sT = ws;                       // 32*1024 floats (128 KB)
  float* t  = ws + DM * LSEQ;           // 1024*32*64 floats (8 MB)
  size_t need = (size_t)(DM * LSEQ + (size_t)LSEQ * DM * PD) * sizeof(float);

  if (ws_size >= need) {
    k_prep<true><<<LSEQ / 4, 256, 0, stream>>>(seq, W1, b1, W2, sT, t);
    k_main<true><<<LSEQ * NJT, 256, 0, stream>>>(sT, t, W2, b2, pair, out);
  } else {
    k_prep<false><<<LSEQ / 4, 256, 0, stream>>>(seq, W1, b1, W2, sT, nullptr);
    k_main<false><<<LSEQ * NJT, 256, 0, stream>>>(sT, nullptr, W2, b2, pair, out);
  }
}

// Round 5
// 129.508 us; speedup vs baseline: 1.5638x; 1.0044x over previous
//
#include <hip/hip_runtime.h>
#include <stdint.h>

#define LSEQ 1024
#define INDIM 256
#define DM 32
#define PD 64
#define JT 256
#define NJT (LSEQ / JT)   // 4

typedef float f32x4 __attribute__((ext_vector_type(4)));

__device__ __forceinline__ void fma4(f32x4& a, float s, const f32x4& t) {
  a.x = fmaf(s, t.x, a.x); a.y = fmaf(s, t.y, a.y);
  a.z = fmaf(s, t.z, a.z); a.w = fmaf(s, t.w, a.w);
}

// async global->LDS, 16B per lane. lds base is wave-uniform; HW adds lane*16.
// global src is per-lane (pass g + lane*4 floats).
__device__ __forceinline__ void g2l16(const float* g, float* l) {
  __builtin_amdgcn_global_load_lds(
      (__attribute__((address_space(1))) void*)g,
      (__attribute__((address_space(3))) void*)l, 16, 0, 0);
}

// Fused prep, 4 rows per block:
//   s[i][c] = seq[i,:]@W1[:,c] + b1[c]  -> sT[c][i]
//   t[i][c][p] = sum_d s[i][d] * W2[(c*DM+d)*PD+p]
template<bool WRT>
__global__ __launch_bounds__(256) void k_prep(const float* __restrict__ seq,
    const float* __restrict__ W1, const float* __restrict__ b1,
    const float* __restrict__ W2, float* __restrict__ sT,
    float* __restrict__ t_out) {
  int i0 = blockIdx.x * 4;
  int tid = threadIdx.x;
  __shared__ float srow[4][INDIM];
  __shared__ float part[4][2][DM];
  __shared__ float si[4][DM];
  ((f32x4*)&srow[0][0])[tid] =
      ((const f32x4*)(seq + (size_t)i0 * INDIM))[tid];
  __syncthreads();
  {
    int c = tid & 31, dseg = (tid >> 5) & 1, il = tid >> 6;
    float a = 0.f;
    #pragma unroll 16
    for (int d = 0; d < 128; ++d)
      a = fmaf(srow[il][dseg * 128 + d], W1[(dseg * 128 + d) * DM + c], a);
    part[il][dseg][c] = a;
  }
  __syncthreads();
  if (tid < 128) {
    int il = tid >> 5, c = tid & 31;
    float a = b1[c] + part[il][0][c] + part[il][1][c];
    si[il][c] = a;
    sT[c * LSEQ + i0 + il] = a;
  }
  __syncthreads();
  if constexpr (WRT) {
    int p = tid & 63, c0 = tid >> 6;
    #pragma unroll
    for (int k = 0; k < 8; ++k) {
      int c = c0 * 8 + k;
      float a0 = 0.f, a1 = 0.f, a2 = 0.f, a3 = 0.f;
      #pragma unroll
      for (int d = 0; d < DM; ++d) {
        float w = W2[(c * DM + d) * PD + p];
        a0 = fmaf(si[0][d], w, a0);
        a1 = fmaf(si[1][d], w, a1);
        a2 = fmaf(si[2][d], w, a2);
        a3 = fmaf(si[3][d], w, a3);
      }
      t_out[((size_t)(i0 + 0) * DM + c) * PD + p] = a0;
      t_out[((size_t)(i0 + 1) * DM + c) * PD + p] = a1;
      t_out[((size_t)(i0 + 2) * DM + c) * PD + p] = a2;
      t_out[((size_t)(i0 + 3) * DM + c) * PD + p] = a3;
    }
  }
}

// out[i][j][p] = sum_c t[i][c][p]*s[j][c] + b2[p] + pair[i][j][p]
// block: fixed i, JT=256 j's, all 64 p; thread tile 8j x 8p.
// t/s staged via global_load_lds (no VGPR); pair loaded straight into acc.
template<bool TPRE>
__global__ __launch_bounds__(256) void k_main(const float* __restrict__ sT,
    const float* __restrict__ tg, const float* __restrict__ W2,
    const float* __restrict__ b2, const float* __restrict__ pair,
    float* __restrict__ out) {
  __shared__ float t_lds[DM][PD];    // 8 KB
  __shared__ float s_lds[DM][JT];    // 32 KB -> 40 KB total, 4 blocks/CU
  int tid = threadIdx.x;
  // XCD-chunked bijective swizzle (4096 % 8 == 0): XCD k gets i-band
  // [k*128,(k+1)*128) -> t[i] reused 4x within one XCD's L2.
  int bid = ((blockIdx.x & 7) << 9) + (blockIdx.x >> 3);
  int i = bid >> 2;
  int jt = (bid & (NJT - 1)) * JT;
  int pl = tid & 7;           // p = pl*4..+3 (acc0) and 32+pl*4..+3 (acc1)
  int jg = tid >> 3;          // 0..31: j = jt + jg*8 + jj
  int lane = tid & 63, w = tid >> 6;

  // 1) async staging, issued first (L2-resident sources)
  if constexpr (TPRE) {
    const float* tb = tg + (size_t)i * (DM * PD) + w * 512 + lane * 4;
    float* tl = &t_lds[0][0] + w * 512;
    g2l16(tb, tl);
    g2l16(tb + 256, tl + 256);
  }
  {
    // s_lds[c][0..255] <- sT[c][jt..jt+256); wave w covers c in [w*8,w*8+8)
    const float* sb = sT + (size_t)(w * 8) * LSEQ + jt + lane * 4;
    float* sl = &s_lds[w * 8][0];
    #pragma unroll
    for (int q = 0; q < 8; ++q)
      g2l16(sb + q * LSEQ, sl + q * JT);
  }

  // 2) pair loads straight into accumulators (complete under stage+barrier)
  size_t rowbase = (size_t)i * (LSEQ * PD) + (size_t)(jt + jg * 8) * PD;
  const f32x4* pp = (const f32x4*)(pair + rowbase);
  f32x4 acc0[8], acc1[8];
  #pragma unroll
  for (int jj = 0; jj < 8; ++jj) {
    acc0[jj] = __builtin_nontemporal_load(&pp[jj * 16 + pl]);
    acc1[jj] = __builtin_nontemporal_load(&pp[jj * 16 + 8 + pl]);
  }

  if constexpr (!TPRE) {
    __shared__ float sish[DM];
    if (tid < DM) sish[tid] = sT[tid * LSEQ + i];
    __syncthreads();
    int p = tid & 63, c0 = tid >> 6;
    #pragma unroll
    for (int k = 0; k < 8; ++k) {
      int c = c0 * 8 + k;
      float acc = 0.f;
      #pragma unroll
      for (int d = 0; d < DM; ++d)
        acc = fmaf(sish[d], W2[(c * DM + d) * PD + p], acc);
      t_lds[c][p] = acc;
    }
  }
  __syncthreads();

  // 3) contraction over c: 4 LDS reads, 64 FMAs per iter
  const f32x4* t4 = (const f32x4*)&t_lds[0][0];  // [c*16 + pidx]
  const f32x4* s4 = (const f32x4*)&s_lds[0][0];  // [c*64 + jg*2 + {0,1}]
  #pragma unroll 8
  for (int c = 0; c < DM; ++c) {
    f32x4 t0 = t4[c * 16 + pl];
    f32x4 t1 = t4[c * 16 + 8 + pl];
    f32x4 sA = s4[c * 64 + jg * 2];
    f32x4 sB = s4[c * 64 + jg * 2 + 1];
    fma4(acc0[0], sA.x, t0); fma4(acc1[0], sA.x, t1);
    fma4(acc0[1], sA.y, t0); fma4(acc1[1], sA.y, t1);
    fma4(acc0[2], sA.z, t0); fma4(acc1[2], sA.z, t1);
    fma4(acc0[3], sA.w, t0); fma4(acc1[3], sA.w, t1);
    fma4(acc0[4], sB.x, t0); fma4(acc1[4], sB.x, t1);
    fma4(acc0[5], sB.y, t0); fma4(acc1[5], sB.y, t1);
    fma4(acc0[6], sB.z, t0); fma4(acc1[6], sB.z, t1);
    fma4(acc0[7], sB.w, t0); fma4(acc1[7], sB.w, t1);
  }

  // 4) bias + pure stores
  const f32x4* b24 = (const f32x4*)b2;
  f32x4 b0 = b24[pl], b1v = b24[8 + pl];
  f32x4* po = (f32x4*)(out + rowbase);
  #pragma unroll
  for (int jj = 0; jj < 8; ++jj) {
    __builtin_nontemporal_store(acc0[jj] + b0, &po[jj * 16 + pl]);
    __builtin_nontemporal_store(acc1[jj] + b1v, &po[jj * 16 + 8 + pl]);
  }
}

extern "C" void kernel_launch(void* const* d_in, const int* in_sizes, int n_in,
                              void* d_out, int out_size, void* d_ws, size_t ws_size,
                              hipStream_t stream) {
  const float* seq  = (const float*)d_in[0];
  const float* pair = (const float*)d_in[1];
  const float* W1   = (const float*)d_in[2];
  const float* b1   = (const float*)d_in[3];
  const float* W2   = (const float*)d_in[4];
  const float* b2   = (const float*)d_in[5];
  float* out = (float*)d_out;
  float* ws  = (float*)d_ws;

  float* sT = ws;                       // 32*1024 floats (128 KB)
  float* t  = ws + DM * LSEQ;           // 1024*32*64 floats (8 MB)
  size_t need = (size_t)(DM * LSEQ + (size_t)LSEQ * DM * PD) * sizeof(float);

  if (ws_size >= need) {
    k_prep<true><<<LSEQ / 4, 256, 0, stream>>>(seq, W1, b1, W2, sT, t);
    k_main<true><<<LSEQ * NJT, 256, 0, stream>>>(sT, t, W2, b2, pair, out);
  } else {
    k_prep<false><<<LSEQ / 4, 256, 0, stream>>>(seq, W1, b1, W2, sT, nullptr);
    k_main<false><<<LSEQ * NJT, 256, 0, stream>>>(sT, nullptr, W2, b2, pair, out);
  }
}